// Round 10
// baseline (137.651 us; speedup 1.0000x reference)
//
#include <hip/hip_runtime.h>
#include <hip/hip_bf16.h>

typedef __attribute__((ext_vector_type(8))) short bf16x8;
typedef __attribute__((ext_vector_type(4))) float f32x4;

__device__ __forceinline__ unsigned int pk2(float a, float b) {
  union { __hip_bfloat162 h; unsigned int u; } cv;
  cv.h = __float22bfloat162_rn(make_float2(a, b));   // v_cvt_pk_bf16_f32
  return cv.u;
}
__device__ __forceinline__ unsigned short f2bf(float f) {
  unsigned int u = __float_as_uint(f);
  u += 0x7FFFu + ((u >> 16) & 1u);
  return (unsigned short)(u >> 16);
}

// Raw barrier WITHOUT the vmcnt(0) drain __syncthreads would emit:
// producer LDS ops retired (lgkmcnt), then s_barrier. Global prefetch loads
// stay in flight across it.
__device__ __forceinline__ void lgkm_barrier() {
  asm volatile("s_waitcnt lgkmcnt(0)" ::: "memory");
  __builtin_amdgcn_s_barrier();
}

// qw[n][e] = scale * sum_d query[n][d] * W[d][e]   (N=64, E=256), stored bf16
__global__ void __launch_bounds__(256) qw_kernel(const float* __restrict__ q,
                                                 const float* __restrict__ W,
                                                 unsigned short* __restrict__ qw) {
  int n = blockIdx.x, e = threadIdx.x;
  float acc = 0.f;
  #pragma unroll 8
  for (int d = 0; d < 256; ++d) acc = fmaf(q[n * 256 + d], W[d * 256 + e], acc);
  qw[n * 256 + e] = f2bf(acc * 0.0625f);  // scale = 256^-0.5
}

// 512 blocks x 512 threads; each block runs 4 CONTIGUOUS batches with a
// software pipeline: batch i+1's x rides in 32 VGPRs under batch i's compute.
// All in-loop barriers are lgkm-only (no vmcnt drain). Per-iter global loads
// (qw frags) are issued BEFORE the prefetch so their waits are counted
// (vmcnt<=8), never draining the prefetch. Datapath per batch == R5 (71.5us).
__global__ void __launch_bounds__(512, 4) cross_main(
    const float* __restrict__ x, const float* __restrict__ value,
    const unsigned short* __restrict__ qw, float* __restrict__ out) {

  __shared__ __align__(16) unsigned short lds_x[64 * 268];       // x[f][e] bf16, row 536 B
  __shared__ __align__(16) unsigned char  lds_pool[64 * 68 * 4]; // att f32 / aw bf16 overlay

  float* lds_att = (float*)lds_pool;                  // [64][68] f32
  unsigned short* lds_aw = (unsigned short*)lds_pool; // [64][72] bf16

  const int t = threadIdx.x;
  const int l = t & 63;
  const int w = t >> 6;
  const int l15 = l & 15, l4 = l >> 4;

  // ---- prologue: prefetch batch 0's x; hoist batch-invariant value row ----
  float4 pre[8];
  {
    const float4* xg = (const float4*)(x + (size_t)(4 * blockIdx.x) * 16384);
    #pragma unroll
    for (int it = 0; it < 4; ++it) {
      pre[2 * it]     = xg[2 * (it * 512 + t)];
      pre[2 * it + 1] = xg[2 * (it * 512 + t) + 1];
    }
  }
  const int n_ent = w * 8 + (l >> 3);      // entmax row for this thread
  const int fb_ent = (l & 7) * 8;          // 8 f's per lane
  const float4 va = *(const float4*)(value + n_ent * 64 + fb_ent);
  const float4 vb = *(const float4*)(value + n_ent * 64 + fb_ent + 4);

  #pragma unroll 1
  for (int bi = 0; bi < 4; ++bi) {
    const size_t b = 4 * blockIdx.x + bi;

    // ---- stage: consume pre[] -> bf16 LDS ----
    #pragma unroll
    for (int it = 0; it < 4; ++it) {
      int u = it * 512 + t;
      int f = u >> 5, c8 = u & 31;
      char* dst = (char*)lds_x + f * 536 + c8 * 16;
      *(uint2*)dst       = make_uint2(pk2(pre[2*it].x, pre[2*it].y), pk2(pre[2*it].z, pre[2*it].w));
      *(uint2*)(dst + 8) = make_uint2(pk2(pre[2*it+1].x, pre[2*it+1].y), pk2(pre[2*it+1].z, pre[2*it+1].w));
    }

    // ---- issue this iter's qw A-frags (oldest-first so their waits count <=8) ----
    const int nt = w >> 1, ft0 = (w & 1) * 2;
    bf16x8 qf[8];
    {
      const unsigned short* qa = qw + (nt * 16 + l15) * 256 + l4 * 8;
      #pragma unroll
      for (int kc = 0; kc < 8; ++kc) qf[kc] = *(const bf16x8*)(qa + kc * 32);
    }
    // ---- issue prefetch of batch bi+1 (rides under this batch's compute) ----
    if (bi < 3) {
      const float4* xg1 = (const float4*)(x + (b + 1) * 16384);
      #pragma unroll
      for (int it = 0; it < 4; ++it) {
        pre[2 * it]     = xg1[2 * (it * 512 + t)];
        pre[2 * it + 1] = xg1[2 * (it * 512 + t) + 1];
      }
    }
    __builtin_amdgcn_sched_barrier(0);   // pin load issue above this point
    lgkm_barrier();                      // lds_x ready; prefetch stays in flight

    // ---- GEMM1: att[n][f] = sum_e qw[n][e] * x[f][e] ----
    {
      f32x4 acc0 = {0.f, 0.f, 0.f, 0.f}, acc1 = {0.f, 0.f, 0.f, 0.f};
      const char* rb0 = (const char*)lds_x + (ft0 * 16 + l15) * 536 + l4 * 16;
      const char* rb1 = rb0 + 16 * 536;
      #pragma unroll
      for (int kc = 0; kc < 8; ++kc) {
        union BF { uint2 d[2]; bf16x8 v; };
        BF b0, b1;
        b0.d[0] = *(const uint2*)(rb0 + kc * 64);
        b0.d[1] = *(const uint2*)(rb0 + kc * 64 + 8);
        b1.d[0] = *(const uint2*)(rb1 + kc * 64);
        b1.d[1] = *(const uint2*)(rb1 + kc * 64 + 8);
        acc0 = __builtin_amdgcn_mfma_f32_16x16x32_bf16(qf[kc], b0.v, acc0, 0, 0, 0);
        acc1 = __builtin_amdgcn_mfma_f32_16x16x32_bf16(qf[kc], b1.v, acc1, 0, 0, 0);
      }
      int nrow = nt * 16 + 4 * l4;
      #pragma unroll
      for (int r = 0; r < 4; ++r) {
        lds_att[(nrow + r) * 68 + ft0 * 16 + l15]       = acc0[r];
        lds_att[(nrow + r) * 68 + (ft0 + 1) * 16 + l15] = acc1[r];
      }
    }
    lgkm_barrier();

    // ---- entmax15 (8 lanes/row) + aw = gate * value ----
    {
      f32x4 z0 = *(const f32x4*)&lds_att[n_ent * 68 + fb_ent];
      f32x4 z1 = *(const f32x4*)&lds_att[n_ent * 68 + fb_ent + 4];
      lgkm_barrier();               // att dead; aw may overwrite pool
      float z[8];
      #pragma unroll
      for (int k = 0; k < 4; ++k) { z[k] = z0[k] * 0.5f; z[k + 4] = z1[k] * 0.5f; }
      float m = fmaxf(fmaxf(fmaxf(z[0], z[1]), fmaxf(z[2], z[3])),
                      fmaxf(fmaxf(z[4], z[5]), fmaxf(z[6], z[7])));
      m = fmaxf(m, __shfl_xor(m, 1));
      m = fmaxf(m, __shfl_xor(m, 2));
      m = fmaxf(m, __shfl_xor(m, 4));
      float tau = m - 1.0f;         // Newton from bracket-lo: monotone from below
      #pragma unroll
      for (int it = 0; it < 12; ++it) {
        float s0 = 0.f, s1 = 0.f, q0 = 0.f, q1 = 0.f;
        #pragma unroll
        for (int k = 0; k < 4; ++k) {
          float d0 = fmaxf(z[k] - tau, 0.f);
          float d1 = fmaxf(z[k + 4] - tau, 0.f);
          s0 = fmaf(d0, d0, s0); q0 += d0;
          s1 = fmaf(d1, d1, s1); q1 += d1;
        }
        float s = s0 + s1, q = q0 + q1;
        s += __shfl_xor(s, 1); s += __shfl_xor(s, 2); s += __shfl_xor(s, 4);
        q += __shfl_xor(q, 1); q += __shfl_xor(q, 2); q += __shfl_xor(q, 4);
        tau += (s - 1.0f) * 0.5f * __builtin_amdgcn_rcpf(q);
      }
      float p[8]; float S = 0.f;
      #pragma unroll
      for (int k = 0; k < 8; ++k) { float d = fmaxf(z[k] - tau, 0.f); p[k] = d * d; S += p[k]; }
      S += __shfl_xor(S, 1); S += __shfl_xor(S, 2); S += __shfl_xor(S, 4);
      float invS = 1.0f / S;
      uint4 pkv;
      pkv.x = pk2(p[0] * invS * va.x, p[1] * invS * va.y);
      pkv.y = pk2(p[2] * invS * va.z, p[3] * invS * va.w);
      pkv.z = pk2(p[4] * invS * vb.x, p[5] * invS * vb.y);
      pkv.w = pk2(p[6] * invS * vb.z, p[7] * invS * vb.w);
      *(uint4*)&lds_aw[n_ent * 72 + fb_ent] = pkv;
    }
    lgkm_barrier();

    // ---- GEMM2: out[n][e] = exp( sum_f aw[n][f] * x[f][e] ) ----
    {
      const int te0 = 2 * w;
      f32x4 acc[4][2];
      #pragma unroll
      for (int nt2 = 0; nt2 < 4; ++nt2) {
        acc[nt2][0] = (f32x4){0.f, 0.f, 0.f, 0.f};
        acc[nt2][1] = (f32x4){0.f, 0.f, 0.f, 0.f};
      }
      #pragma unroll
      for (int kc = 0; kc < 2; ++kc) {
        bf16x8 a[4];
        #pragma unroll
        for (int nt2 = 0; nt2 < 4; ++nt2)
          a[nt2] = *(const bf16x8*)&lds_aw[(nt2 * 16 + l15) * 72 + kc * 32 + l4 * 8];
        const char* gp = (const char*)lds_x + (kc * 32 + l4 * 8) * 536 + (te0 * 16 + l15) * 2;
        #pragma unroll
        for (int j = 0; j < 2; ++j) {
          union { unsigned short u[8]; bf16x8 v; } bb;   // transposed gather (2-way, free)
          #pragma unroll
          for (int i = 0; i < 8; ++i)
            bb.u[i] = *(const unsigned short*)(gp + i * 536 + j * 32);
          #pragma unroll
          for (int nt2 = 0; nt2 < 4; ++nt2)
            acc[nt2][j] = __builtin_amdgcn_mfma_f32_16x16x32_bf16(a[nt2], bb.v, acc[nt2][j], 0, 0, 0);
        }
      }
      float* ob = out + b * 16384;
      #pragma unroll
      for (int nt2 = 0; nt2 < 4; ++nt2)
        #pragma unroll
        for (int j = 0; j < 2; ++j)
          #pragma unroll
          for (int r = 0; r < 4; ++r)
            ob[(nt2 * 16 + 4 * l4 + r) * 256 + (te0 + j) * 16 + l15] = __expf(acc[nt2][j][r]);
    }
    lgkm_barrier();   // GEMM2 LDS reads retired before next stage overwrites lds_x
  }
}

extern "C" void kernel_launch(void* const* d_in, const int* in_sizes, int n_in,
                              void* d_out, int out_size, void* d_ws, size_t ws_size,
                              hipStream_t stream) {
  const float* x     = (const float*)d_in[0];
  const float* W     = (const float*)d_in[1];
  const float* q     = (const float*)d_in[2];
  const float* value = (const float*)d_in[3];
  float* out = (float*)d_out;
  unsigned short* qw = (unsigned short*)d_ws;  // 64*256 bf16 = 32 KB scratch

  qw_kernel<<<dim3(64), dim3(256), 0, stream>>>(q, W, qw);
  cross_main<<<dim3(512), dim3(512), 0, stream>>>(x, value, qw, out);
}

// Round 11
// 73.710 us; speedup vs baseline: 1.8675x; 1.8675x over previous
//
#include <hip/hip_runtime.h>
#include <hip/hip_bf16.h>

typedef __attribute__((ext_vector_type(8))) short bf16x8;
typedef __attribute__((ext_vector_type(4))) float f32x4;

__device__ __forceinline__ unsigned int pk2(float a, float b) {
  union { __hip_bfloat162 h; unsigned int u; } cv;
  cv.h = __float22bfloat162_rn(make_float2(a, b));   // v_cvt_pk_bf16_f32
  return cv.u;
}
__device__ __forceinline__ unsigned short f2bf(float f) {
  unsigned int u = __float_as_uint(f);
  u += 0x7FFFu + ((u >> 16) & 1u);
  return (unsigned short)(u >> 16);
}

// qw[n][e] = scale * sum_d query[n][d] * W[d][e]   (N=64, E=256), stored bf16
__global__ void __launch_bounds__(256) qw_kernel(const float* __restrict__ q,
                                                 const float* __restrict__ W,
                                                 unsigned short* __restrict__ qw) {
  int n = blockIdx.x, e = threadIdx.x;
  float acc = 0.f;
  #pragma unroll 8
  for (int d = 0; d < 256; ++d) acc = fmaf(q[n * 256 + d], W[d * 256 + e], acc);
  qw[n * 256 + e] = f2bf(acc * 0.0625f);  // scale = 256^-0.5
}

// One block per batch b. 512 threads = 8 waves.  (R5 structure, measured 71.5us.)
// R11: single change vs R5 — out-stores are NONTEMPORAL so the 131 MB write
// stream doesn't allocate in L2/L3; x (134 MB) then stays L3-resident across
// replays (FETCH_SIZE should collapse), HBM carries only the write stream.
__global__ void __launch_bounds__(512, 6) cross_main(
    const float* __restrict__ x, const float* __restrict__ value,
    const unsigned short* __restrict__ qw, float* __restrict__ out) {

  __shared__ __align__(16) unsigned short lds_x[64 * 268];       // x[f][e] bf16, row = 536 B
  __shared__ __align__(16) unsigned char  lds_pool[64 * 68 * 4]; // att (f32) then aw (bf16)

  float* lds_att = (float*)lds_pool;                  // [64][68] f32: GEMM1 -> entmax
  unsigned short* lds_aw = (unsigned short*)lds_pool; // [64][72] bf16: entmax -> GEMM2

  const int t = threadIdx.x;
  const int b = blockIdx.x;
  const int l = t & 63;
  const int w = t >> 6;
  const int l15 = l & 15, l4 = l >> 4;

  // ---- stage x[b] (fp32 global) -> bf16 LDS via cvt_pk; 8 floats/thread/iter ----
  {
    const float4* xg = (const float4*)(x + (size_t)b * 16384);
    #pragma unroll
    for (int it = 0; it < 4; ++it) {
      int u = it * 512 + t;            // 8-float unit, 0..2047
      float4 v0 = xg[2 * u], v1 = xg[2 * u + 1];
      int f = u >> 5, c8 = u & 31;
      char* dst = (char*)lds_x + f * 536 + c8 * 16;   // 8-aligned
      *(uint2*)dst       = make_uint2(pk2(v0.x, v0.y), pk2(v0.z, v0.w));
      *(uint2*)(dst + 8) = make_uint2(pk2(v1.x, v1.y), pk2(v1.z, v1.w));
    }
  }
  __syncthreads();

  // ---- att[n][f] = sum_e qw[n][e] * x[f][e]  (M=n, N=f, K=e) ----
  {
    int nt = w >> 1, ft0 = (w & 1) * 2;    // wave tile: 1 n-tile x 2 f-tiles
    f32x4 acc0 = {0.f, 0.f, 0.f, 0.f}, acc1 = {0.f, 0.f, 0.f, 0.f};
    const unsigned short* qa = qw + (nt * 16 + l15) * 256 + l4 * 8;
    const char* rb0 = (const char*)lds_x + (ft0 * 16 + l15) * 536 + l4 * 16;
    const char* rb1 = rb0 + 16 * 536;
    #pragma unroll
    for (int kc = 0; kc < 8; ++kc) {
      union BF { uint2 d[2]; bf16x8 v; };
      bf16x8 a = *(const bf16x8*)(qa + kc * 32);       // global (L1/L2-resident)
      BF b0, b1;
      b0.d[0] = *(const uint2*)(rb0 + kc * 64);
      b0.d[1] = *(const uint2*)(rb0 + kc * 64 + 8);
      b1.d[0] = *(const uint2*)(rb1 + kc * 64);
      b1.d[1] = *(const uint2*)(rb1 + kc * 64 + 8);
      acc0 = __builtin_amdgcn_mfma_f32_16x16x32_bf16(a, b0.v, acc0, 0, 0, 0);
      acc1 = __builtin_amdgcn_mfma_f32_16x16x32_bf16(a, b1.v, acc1, 0, 0, 0);
    }
    int nrow = nt * 16 + 4 * l4;
    #pragma unroll
    for (int r = 0; r < 4; ++r) {
      lds_att[(nrow + r) * 68 + ft0 * 16 + l15]       = acc0[r];
      lds_att[(nrow + r) * 68 + (ft0 + 1) * 16 + l15] = acc1[r];
    }
  }
  __syncthreads();

  // ---- entmax15 over f per row (8 lanes/row); aw[n][f] = gate * value[n][f] ----
  {
    int n = w * 8 + (l >> 3);
    int fb = (l & 7) * 8;
    f32x4 z0 = *(const f32x4*)&lds_att[n * 68 + fb];
    f32x4 z1 = *(const f32x4*)&lds_att[n * 68 + fb + 4];
    __syncthreads();                // att dead; aw may overwrite pool
    float z[8];
    #pragma unroll
    for (int k = 0; k < 4; ++k) { z[k] = z0[k] * 0.5f; z[k + 4] = z1[k] * 0.5f; }
    float m = fmaxf(fmaxf(fmaxf(z[0], z[1]), fmaxf(z[2], z[3])),
                    fmaxf(fmaxf(z[4], z[5]), fmaxf(z[6], z[7])));
    m = fmaxf(m, __shfl_xor(m, 1));
    m = fmaxf(m, __shfl_xor(m, 2));
    m = fmaxf(m, __shfl_xor(m, 4));
    // Newton on f(tau) = sum (z-tau)_+^2 - 1: convex decreasing, start at bracket-lo
    // (f>=0) => monotone from below, quadratic endgame. 12 iters >> f32 fixed point.
    float tau = m - 1.0f;
    #pragma unroll
    for (int it = 0; it < 12; ++it) {
      float s0 = 0.f, s1 = 0.f, q0 = 0.f, q1 = 0.f;
      #pragma unroll
      for (int k = 0; k < 4; ++k) {
        float d0 = fmaxf(z[k] - tau, 0.f);
        float d1 = fmaxf(z[k + 4] - tau, 0.f);
        s0 = fmaf(d0, d0, s0); q0 += d0;
        s1 = fmaf(d1, d1, s1); q1 += d1;
      }
      float s = s0 + s1, q = q0 + q1;
      s += __shfl_xor(s, 1); s += __shfl_xor(s, 2); s += __shfl_xor(s, 4);
      q += __shfl_xor(q, 1); q += __shfl_xor(q, 2); q += __shfl_xor(q, 4);
      tau += (s - 1.0f) * 0.5f * __builtin_amdgcn_rcpf(q);
    }
    float p[8]; float S = 0.f;
    #pragma unroll
    for (int k = 0; k < 8; ++k) { float d = fmaxf(z[k] - tau, 0.f); p[k] = d * d; S += p[k]; }
    S += __shfl_xor(S, 1); S += __shfl_xor(S, 2); S += __shfl_xor(S, 4);
    float invS = 1.0f / S;
    const float4* vg = (const float4*)(value + n * 64 + fb);
    float4 va = vg[0], vb = vg[1];
    uint4 pkv;
    pkv.x = pk2(p[0] * invS * va.x, p[1] * invS * va.y);
    pkv.y = pk2(p[2] * invS * va.z, p[3] * invS * va.w);
    pkv.z = pk2(p[4] * invS * vb.x, p[5] * invS * vb.y);
    pkv.w = pk2(p[6] * invS * vb.z, p[7] * invS * vb.w);
    *(uint4*)&lds_aw[n * 72 + fb] = pkv;   // (n*72+fb)*2 is 16B-aligned
  }
  __syncthreads();

  // ---- out[n][e] = exp( sum_f aw[n][f] * x[f][e] )  (M=n, N=e, K=f) ----
  // Wave w owns e-tiles {2w,2w+1} and all 4 n-tiles; gather is 2-way (free) at stride 536.
  {
    const int te0 = 2 * w;
    f32x4 acc[4][2];
    #pragma unroll
    for (int nt = 0; nt < 4; ++nt) {
      acc[nt][0] = (f32x4){0.f, 0.f, 0.f, 0.f};
      acc[nt][1] = (f32x4){0.f, 0.f, 0.f, 0.f};
    }
    #pragma unroll
    for (int kc = 0; kc < 2; ++kc) {
      bf16x8 a[4];
      #pragma unroll
      for (int nt = 0; nt < 4; ++nt)
        a[nt] = *(const bf16x8*)&lds_aw[(nt * 16 + l15) * 72 + kc * 32 + l4 * 8];
      const char* gp = (const char*)lds_x + (kc * 32 + l4 * 8) * 536 + (te0 * 16 + l15) * 2;
      #pragma unroll
      for (int j = 0; j < 2; ++j) {
        union { unsigned short u[8]; bf16x8 v; } bb;   // transposed gather of x
        #pragma unroll
        for (int i = 0; i < 8; ++i)
          bb.u[i] = *(const unsigned short*)(gp + i * 536 + j * 32);
        #pragma unroll
        for (int nt = 0; nt < 4; ++nt)
          acc[nt][j] = __builtin_amdgcn_mfma_f32_16x16x32_bf16(a[nt], bb.v, acc[nt][j], 0, 0, 0);
      }
    }
    float* ob = out + (size_t)b * 16384;
    #pragma unroll
    for (int nt = 0; nt < 4; ++nt) {
      #pragma unroll
      for (int j = 0; j < 2; ++j) {
        #pragma unroll
        for (int r = 0; r < 4; ++r) {
          // NONTEMPORAL: out is write-once, never re-read; don't pollute L2/L3
          __builtin_nontemporal_store(
              __expf(acc[nt][j][r]),
              &ob[(nt * 16 + 4 * l4 + r) * 256 + (te0 + j) * 16 + l15]);
        }
      }
    }
  }
}

extern "C" void kernel_launch(void* const* d_in, const int* in_sizes, int n_in,
                              void* d_out, int out_size, void* d_ws, size_t ws_size,
                              hipStream_t stream) {
  const float* x     = (const float*)d_in[0];
  const float* W     = (const float*)d_in[1];
  const float* q     = (const float*)d_in[2];
  const float* value = (const float*)d_in[3];
  float* out = (float*)d_out;
  unsigned short* qw = (unsigned short*)d_ws;  // 64*256 bf16 = 32 KB scratch

  qw_kernel<<<dim3(64), dim3(256), 0, stream>>>(q, W, qw);
  cross_main<<<dim3(2048), dim3(512), 0, stream>>>(x, value, qw, out);
}

// Round 14
// 69.776 us; speedup vs baseline: 1.9727x; 1.0564x over previous
//
#include <hip/hip_runtime.h>
#include <hip/hip_bf16.h>

typedef __attribute__((ext_vector_type(8))) short bf16x8;
typedef __attribute__((ext_vector_type(4))) float f32x4;

__device__ __forceinline__ unsigned int pk2(float a, float b) {
  union { __hip_bfloat162 h; unsigned int u; } cv;
  cv.h = __float22bfloat162_rn(make_float2(a, b));   // v_cvt_pk_bf16_f32
  return cv.u;
}
__device__ __forceinline__ unsigned short f2bf(float f) {
  unsigned int u = __float_as_uint(f);
  u += 0x7FFFu + ((u >> 16) & 1u);
  return (unsigned short)(u >> 16);
}

// DPP quad-perm cross-lane (VALU, ~2cy) replacing ds_bpermute (~40cy DS):
// xor1 = quad_perm [1,0,3,2] = 0xB1; xor2 = quad_perm [2,3,0,1] = 0x4E.
__device__ __forceinline__ float dpp_xor1(float v) {
  return __int_as_float(__builtin_amdgcn_update_dpp(
      0, __float_as_int(v), 0xB1, 0xF, 0xF, true));
}
__device__ __forceinline__ float dpp_xor2(float v) {
  return __int_as_float(__builtin_amdgcn_update_dpp(
      0, __float_as_int(v), 0x4E, 0xF, 0xF, true));
}

// qw[n][e] = scale * sum_d query[n][d] * W[d][e]   (N=64, E=256), stored bf16
__global__ void __launch_bounds__(256) qw_kernel(const float* __restrict__ q,
                                                 const float* __restrict__ W,
                                                 unsigned short* __restrict__ qw) {
  int n = blockIdx.x, e = threadIdx.x;
  float acc = 0.f;
  #pragma unroll 8
  for (int d = 0; d < 256; ++d) acc = fmaf(q[n * 256 + d], W[d * 256 + e], acc);
  qw[n * 256 + e] = f2bf(acc * 0.0625f);  // scale = 256^-0.5
}

// One block per batch b. 512 threads = 8 waves.  (R5 structure, best = 71.5us.)
// R12: entmax reductions use DPP for the xor1/xor2 stages (bit-identical
// butterfly, VALU instead of DS) — only xor4 remains a shfl. Newton 12->10.
__global__ void __launch_bounds__(512, 6) cross_main(
    const float* __restrict__ x, const float* __restrict__ value,
    const unsigned short* __restrict__ qw, float* __restrict__ out) {

  __shared__ __align__(16) unsigned short lds_x[64 * 268];       // x[f][e] bf16, row = 536 B
  __shared__ __align__(16) unsigned char  lds_pool[64 * 68 * 4]; // att (f32) then aw (bf16)

  float* lds_att = (float*)lds_pool;                  // [64][68] f32: GEMM1 -> entmax
  unsigned short* lds_aw = (unsigned short*)lds_pool; // [64][72] bf16: entmax -> GEMM2

  const int t = threadIdx.x;
  const int b = blockIdx.x;
  const int l = t & 63;
  const int w = t >> 6;
  const int l15 = l & 15, l4 = l >> 4;

  // ---- stage x[b] (fp32 global) -> bf16 LDS via cvt_pk; 8 floats/thread/iter ----
  {
    const float4* xg = (const float4*)(x + (size_t)b * 16384);
    #pragma unroll
    for (int it = 0; it < 4; ++it) {
      int u = it * 512 + t;            // 8-float unit, 0..2047
      float4 v0 = xg[2 * u], v1 = xg[2 * u + 1];
      int f = u >> 5, c8 = u & 31;
      char* dst = (char*)lds_x + f * 536 + c8 * 16;   // 8-aligned
      *(uint2*)dst       = make_uint2(pk2(v0.x, v0.y), pk2(v0.z, v0.w));
      *(uint2*)(dst + 8) = make_uint2(pk2(v1.x, v1.y), pk2(v1.z, v1.w));
    }
  }
  __syncthreads();

  // ---- att[n][f] = sum_e qw[n][e] * x[f][e]  (M=n, N=f, K=e) ----
  {
    int nt = w >> 1, ft0 = (w & 1) * 2;    // wave tile: 1 n-tile x 2 f-tiles
    f32x4 acc0 = {0.f, 0.f, 0.f, 0.f}, acc1 = {0.f, 0.f, 0.f, 0.f};
    const unsigned short* qa = qw + (nt * 16 + l15) * 256 + l4 * 8;
    const char* rb0 = (const char*)lds_x + (ft0 * 16 + l15) * 536 + l4 * 16;
    const char* rb1 = rb0 + 16 * 536;
    #pragma unroll
    for (int kc = 0; kc < 8; ++kc) {
      union BF { uint2 d[2]; bf16x8 v; };
      bf16x8 a = *(const bf16x8*)(qa + kc * 32);       // global (L1/L2-resident)
      BF b0, b1;
      b0.d[0] = *(const uint2*)(rb0 + kc * 64);
      b0.d[1] = *(const uint2*)(rb0 + kc * 64 + 8);
      b1.d[0] = *(const uint2*)(rb1 + kc * 64);
      b1.d[1] = *(const uint2*)(rb1 + kc * 64 + 8);
      acc0 = __builtin_amdgcn_mfma_f32_16x16x32_bf16(a, b0.v, acc0, 0, 0, 0);
      acc1 = __builtin_amdgcn_mfma_f32_16x16x32_bf16(a, b1.v, acc1, 0, 0, 0);
    }
    int nrow = nt * 16 + 4 * l4;
    #pragma unroll
    for (int r = 0; r < 4; ++r) {
      lds_att[(nrow + r) * 68 + ft0 * 16 + l15]       = acc0[r];
      lds_att[(nrow + r) * 68 + (ft0 + 1) * 16 + l15] = acc1[r];
    }
  }
  __syncthreads();

  // ---- entmax15 over f per row (8 lanes/row); aw[n][f] = gate * value[n][f] ----
  {
    int n = w * 8 + (l >> 3);
    int fb = (l & 7) * 8;
    f32x4 z0 = *(const f32x4*)&lds_att[n * 68 + fb];
    f32x4 z1 = *(const f32x4*)&lds_att[n * 68 + fb + 4];
    __syncthreads();                // att dead; aw may overwrite pool
    float z[8];
    #pragma unroll
    for (int k = 0; k < 4; ++k) { z[k] = z0[k] * 0.5f; z[k + 4] = z1[k] * 0.5f; }
    float m = fmaxf(fmaxf(fmaxf(z[0], z[1]), fmaxf(z[2], z[3])),
                    fmaxf(fmaxf(z[4], z[5]), fmaxf(z[6], z[7])));
    m = fmaxf(m, dpp_xor1(m));
    m = fmaxf(m, dpp_xor2(m));
    m = fmaxf(m, __shfl_xor(m, 4));
    // Newton on f(tau) = sum (z-tau)_+^2 - 1: convex decreasing, start at
    // bracket-lo (f>=0) => monotone from below, quadratic endgame.
    float tau = m - 1.0f;
    #pragma unroll
    for (int it = 0; it < 10; ++it) {
      float s0 = 0.f, s1 = 0.f, q0 = 0.f, q1 = 0.f;
      #pragma unroll
      for (int k = 0; k < 4; ++k) {
        float d0 = fmaxf(z[k] - tau, 0.f);
        float d1 = fmaxf(z[k + 4] - tau, 0.f);
        s0 = fmaf(d0, d0, s0); q0 += d0;
        s1 = fmaf(d1, d1, s1); q1 += d1;
      }
      float s = s0 + s1, q = q0 + q1;
      s += dpp_xor1(s); s += dpp_xor2(s); s += __shfl_xor(s, 4);
      q += dpp_xor1(q); q += dpp_xor2(q); q += __shfl_xor(q, 4);
      tau += (s - 1.0f) * 0.5f * __builtin_amdgcn_rcpf(q);
    }
    float p[8]; float S = 0.f;
    #pragma unroll
    for (int k = 0; k < 8; ++k) { float d = fmaxf(z[k] - tau, 0.f); p[k] = d * d; S += p[k]; }
    S += dpp_xor1(S); S += dpp_xor2(S); S += __shfl_xor(S, 4);
    float invS = 1.0f / S;
    const float4* vg = (const float4*)(value + n * 64 + fb);
    float4 va = vg[0], vb = vg[1];
    uint4 pkv;
    pkv.x = pk2(p[0] * invS * va.x, p[1] * invS * va.y);
    pkv.y = pk2(p[2] * invS * va.z, p[3] * invS * va.w);
    pkv.z = pk2(p[4] * invS * vb.x, p[5] * invS * vb.y);
    pkv.w = pk2(p[6] * invS * vb.z, p[7] * invS * vb.w);
    *(uint4*)&lds_aw[n * 72 + fb] = pkv;   // (n*72+fb)*2 is 16B-aligned
  }
  __syncthreads();

  // ---- out[n][e] = exp( sum_f aw[n][f] * x[f][e] )  (M=n, N=e, K=f) ----
  // Wave w owns e-tiles {2w,2w+1} and all 4 n-tiles; gather 2-way (free) at stride 536.
  {
    const int te0 = 2 * w;
    f32x4 acc[4][2];
    #pragma unroll
    for (int nt = 0; nt < 4; ++nt) {
      acc[nt][0] = (f32x4){0.f, 0.f, 0.f, 0.f};
      acc[nt][1] = (f32x4){0.f, 0.f, 0.f, 0.f};
    }
    #pragma unroll
    for (int kc = 0; kc < 2; ++kc) {
      bf16x8 a[4];
      #pragma unroll
      for (int nt = 0; nt < 4; ++nt)
        a[nt] = *(const bf16x8*)&lds_aw[(nt * 16 + l15) * 72 + kc * 32 + l4 * 8];
      const char* gp = (const char*)lds_x + (kc * 32 + l4 * 8) * 536 + (te0 * 16 + l15) * 2;
      #pragma unroll
      for (int j = 0; j < 2; ++j) {
        union { unsigned short u[8]; bf16x8 v; } bb;   // transposed gather of x
        #pragma unroll
        for (int i = 0; i < 8; ++i)
          bb.u[i] = *(const unsigned short*)(gp + i * 536 + j * 32);
        #pragma unroll
        for (int nt = 0; nt < 4; ++nt)
          acc[nt][j] = __builtin_amdgcn_mfma_f32_16x16x32_bf16(a[nt], bb.v, acc[nt][j], 0, 0, 0);
      }
    }
    float* ob = out + (size_t)b * 16384;
    #pragma unroll
    for (int nt = 0; nt < 4; ++nt) {
      #pragma unroll
      for (int j = 0; j < 2; ++j) {
        #pragma unroll
        for (int r = 0; r < 4; ++r) {
          ob[(nt * 16 + 4 * l4 + r) * 256 + (te0 + j) * 16 + l15] = __expf(acc[nt][j][r]);
        }
      }
    }
  }
}

extern "C" void kernel_launch(void* const* d_in, const int* in_sizes, int n_in,
                              void* d_out, int out_size, void* d_ws, size_t ws_size,
                              hipStream_t stream) {
  const float* x     = (const float*)d_in[0];
  const float* W     = (const float*)d_in[1];
  const float* q     = (const float*)d_in[2];
  const float* value = (const float*)d_in[3];
  float* out = (float*)d_out;
  unsigned short* qw = (unsigned short*)d_ws;  // 64*256 bf16 = 32 KB scratch

  qw_kernel<<<dim3(64), dim3(256), 0, stream>>>(q, W, qw);
  cross_main<<<dim3(2048), dim3(512), 0, stream>>>(x, value, qw, out);
}